// Round 12
// baseline (181.959 us; speedup 1.0000x reference)
//
#include <hip/hip_runtime.h>
#include <hip/hip_bf16.h>
#include <math.h>

namespace {
constexpr int kB  = 64;
constexpr int kNi = 2048;
constexpr int kNo = 32;
constexpr int kDo = 16;
constexpr int kSeg   = kNo * kDo;      // 512 od
constexpr int kSlabs = 256;            // n-slabs
constexpr int kNPer  = kNi / kSlabs;   // 8 n per slab
}

typedef __attribute__((ext_vector_type(4)))  short s4;    // 4 bf16 (2 VGPR)
typedef __attribute__((ext_vector_type(16))) float f16v;  // MFMA C/D

__device__ __forceinline__ f16v mfma_32x32x8_bf16(s4 a, s4 b, f16v c) {
#if __has_builtin(__builtin_amdgcn_mfma_f32_32x32x8bf16_1k)
    return __builtin_amdgcn_mfma_f32_32x32x8bf16_1k(a, b, c, 0, 0, 0);
#else
    asm("v_mfma_f32_32x32x8_bf16 %0, %1, %2, %0" : "+v"(c) : "v"(a), "v"(b));
    return c;
#endif
}

__device__ __forceinline__ unsigned pack_bf16(float lo, float hi) {
    union { __hip_bfloat162 h; unsigned u; } v;
    v.h = __float22bfloat162_rn(make_float2(lo, hi));
    return v.u;
}
__device__ __forceinline__ float bf_lo(unsigned u) { return __uint_as_float(u << 16); }
__device__ __forceinline__ float bf_hi(unsigned u) { return __uint_as_float(u & 0xffff0000u); }

union A2 { int2 i; s4 s; };

// ---------------------------------------------------------------------------
// Prep (verified r10/r11): pack W and x into 32x32x8 MFMA fragment order.
// wPack2 int4 idx ((n*8+w)*64+l): slots {0,1}=mt 2w, {2,3}=mt 2w+1,
//   value = W[n][mt*32+(l&31)][4*(l>>5)+j].
// xPack int2 idx ((n*2+nt)*64+l) = x[nt*32+(l&31)][n][4*(l>>5)+j].
// ---------------------------------------------------------------------------
__global__ __launch_bounds__(256, 4)
void caps_prep(const float* __restrict__ xg, const float* __restrict__ Wg,
               unsigned* __restrict__ wPack2, unsigned* __restrict__ xPack)
{
    const int t = blockIdx.x * 256 + threadIdx.x;
    const int nW = kNi * 16 * 64;
    if (t < nW) {
        const int n = t >> 10, rem = t & 1023, mt = rem >> 6, l = rem & 63;
        const float4 w = *reinterpret_cast<const float4*>(
            Wg + ((size_t)n * kSeg + mt * 32 + (l & 31)) * 8 + 4 * (l >> 5));
        const size_t base = (((size_t)n * 8 + (mt >> 1)) * 64 + l) * 4 + (mt & 1) * 2;
        uint2 u; u.x = pack_bf16(w.x, w.y); u.y = pack_bf16(w.z, w.w);
        *reinterpret_cast<uint2*>(wPack2 + base) = u;
    } else {
        const int t2 = t - nW;
        const int n = t2 >> 7, rem = t2 & 127, nt = rem >> 6, l = rem & 63;
        const float4 v = *reinterpret_cast<const float4*>(
            xg + ((size_t)(nt * 32 + (l & 31)) * kNi + n) * 8 + 4 * (l >> 5));
        uint2 u; u.x = pack_bf16(v.x, v.y); u.y = pack_bf16(v.z, v.w);
        *reinterpret_cast<uint2*>(xPack + (size_t)t2 * 2) = u;
    }
}

// C/D layout (m74/m101-verified): col = l&31 (= b),
// row = (reg&3)+8*(reg>>2)+4*(l>>5); regs 0-7 -> o=2mt, regs 8-15 -> o=2mt+1.

// ---------------------------------------------------------------------------
// Fused route. Grid 512 = 256 slabs x 2 b-halves. Wave w owns mt {2w, 2w+1};
// block covers all 16 mt -> Z closes in-block (Zl[2] double-buffer, 1
// barrier/nn; write Zl[p]/barrier/read Zl[p] separated from next write to
// Zl[p] by 2 barriers -> race-free).
// SINGLE sweep, register diet vs r10 (which spilled at ~130 live):
//   - vsum frags held as PACKED BF16 (vpk 16 regs, was 32): r11 precedent —
//     coupling c itself was bf16 in cbuf and passed at absmax 0.0039.
//   - x_hat tiles packed to bf16 right after the logit step (tp 16 regs carry
//     across the barrier, was 32); accumulate unpacks on the fly (same
//     rounding the bf16 partial store already applies).
// Live ~110 <= 128 cap. PASS==0: pure MFMA accumulate (1/32 in finish).
// ---------------------------------------------------------------------------
template<int PASS>
__global__ __launch_bounds__(512, 2)
void caps_route(const unsigned* __restrict__ wPack2, const unsigned* __restrict__ xPack,
                const float* __restrict__ vsumPack, __hip_bfloat16* __restrict__ partial)
{
    __shared__ float Zl[2][8][32];

    const int tid = threadIdx.x;
    const int blk = blockIdx.x & (kSlabs - 1);
    const int nt  = blockIdx.x >> 8;
    const int w   = __builtin_amdgcn_readfirstlane(tid >> 6);
    const int l   = tid & 63;
    const int b32 = l & 31;
    const int b   = nt * 32 + b32;
    const int hi  = l >> 5;

    // vsum fragments, packed bf16 (C-row order, pre-scaled by log2 e)
    unsigned vpk[2][8];
    if (PASS > 0) {
#pragma unroll
        for (int m = 0; m < 2; ++m) {
            const int mt = 2 * w + m;
            const float4* vp = reinterpret_cast<const float4*>(
                vsumPack + (((size_t)mt * 2 + hi) * 64 + b) * 16);
#pragma unroll
            for (int k = 0; k < 4; ++k) {
                const float4 v = vp[k];
                vpk[m][2 * k + 0] = pack_bf16(v.x, v.y);
                vpk[m][2 * k + 1] = pack_bf16(v.z, v.w);
            }
        }
    }

    float sacc[2][16];
    f16v acc0, acc1;
#pragma unroll
    for (int r = 0; r < 16; ++r) {
        sacc[0][r] = 0.0f; sacc[1][r] = 0.0f;
        acc0[r] = 0.0f;    acc1[r] = 0.0f;
    }

    const int4* wp4 = reinterpret_cast<const int4*>(wPack2);
    const int2* xp2 = reinterpret_cast<const int2*>(xPack);
    const size_t abase = ((size_t)blk * 64 + w) * 64 + l;          // +nn*512
    const size_t xbase = ((size_t)blk * 16 + nt) * 64 + l;         // +nn*128

#pragma unroll
    for (int nn = 0; nn < kNPer; ++nn) {
        const int4 aw = wp4[abase + (size_t)nn * 512];
        const int2 bx = xp2[xbase + (size_t)nn * 128];
        A2 ua0; ua0.i = make_int2(aw.x, aw.y);
        A2 ua1; ua1.i = make_int2(aw.z, aw.w);
        A2 ub;  ub.i  = bx;

        if (PASS == 0) {
            acc0 = mfma_32x32x8_bf16(ua0.s, ub.s, acc0);
            acc1 = mfma_32x32x8_bf16(ua1.s, ub.s, acc1);
        } else {
            float e00, e01, e10, e11;
            unsigned tp0[8], tp1[8];
            {   // tile 0: MFMA -> logit -> e -> bf16 stash
                f16v t0;
#pragma unroll
                for (int r = 0; r < 16; ++r) t0[r] = 0.0f;
                t0 = mfma_32x32x8_bf16(ua0.s, ub.s, t0);
                float a0_ = fmaf(bf_hi(vpk[0][0]), t0[1], bf_lo(vpk[0][0]) * t0[0]);
                float a1_ = fmaf(bf_hi(vpk[0][1]), t0[3], bf_lo(vpk[0][1]) * t0[2]);
                float a2_ = fmaf(bf_hi(vpk[0][2]), t0[5], bf_lo(vpk[0][2]) * t0[4]);
                float a3_ = fmaf(bf_hi(vpk[0][3]), t0[7], bf_lo(vpk[0][3]) * t0[6]);
                float p0 = (a0_ + a1_) + (a2_ + a3_);
                float b0_ = fmaf(bf_hi(vpk[0][4]), t0[9],  bf_lo(vpk[0][4]) * t0[8]);
                float b1_ = fmaf(bf_hi(vpk[0][5]), t0[11], bf_lo(vpk[0][5]) * t0[10]);
                float b2_ = fmaf(bf_hi(vpk[0][6]), t0[13], bf_lo(vpk[0][6]) * t0[12]);
                float b3_ = fmaf(bf_hi(vpk[0][7]), t0[15], bf_lo(vpk[0][7]) * t0[14]);
                float p1 = (b0_ + b1_) + (b2_ + b3_);
                p0 += __shfl_xor(p0, 32);
                p1 += __shfl_xor(p1, 32);
                e00 = exp2f(p0); e01 = exp2f(p1);
#pragma unroll
                for (int k = 0; k < 8; ++k)
                    tp0[k] = pack_bf16(t0[2 * k], t0[2 * k + 1]);
            }
            {   // tile 1
                f16v t1;
#pragma unroll
                for (int r = 0; r < 16; ++r) t1[r] = 0.0f;
                t1 = mfma_32x32x8_bf16(ua1.s, ub.s, t1);
                float a0_ = fmaf(bf_hi(vpk[1][0]), t1[1], bf_lo(vpk[1][0]) * t1[0]);
                float a1_ = fmaf(bf_hi(vpk[1][1]), t1[3], bf_lo(vpk[1][1]) * t1[2]);
                float a2_ = fmaf(bf_hi(vpk[1][2]), t1[5], bf_lo(vpk[1][2]) * t1[4]);
                float a3_ = fmaf(bf_hi(vpk[1][3]), t1[7], bf_lo(vpk[1][3]) * t1[6]);
                float p0 = (a0_ + a1_) + (a2_ + a3_);
                float b0_ = fmaf(bf_hi(vpk[1][4]), t1[9],  bf_lo(vpk[1][4]) * t1[8]);
                float b1_ = fmaf(bf_hi(vpk[1][5]), t1[11], bf_lo(vpk[1][5]) * t1[10]);
                float b2_ = fmaf(bf_hi(vpk[1][6]), t1[13], bf_lo(vpk[1][6]) * t1[12]);
                float b3_ = fmaf(bf_hi(vpk[1][7]), t1[15], bf_lo(vpk[1][7]) * t1[14]);
                float p1 = (b0_ + b1_) + (b2_ + b3_);
                p0 += __shfl_xor(p0, 32);
                p1 += __shfl_xor(p1, 32);
                e10 = exp2f(p0); e11 = exp2f(p1);
#pragma unroll
                for (int k = 0; k < 8; ++k)
                    tp1[k] = pack_bf16(t1[2 * k], t1[2 * k + 1]);
            }

            if (l < 32) Zl[nn & 1][w][l] = (e00 + e01) + (e10 + e11);
            __syncthreads();
            float Z = 0.0f;
#pragma unroll
            for (int w2 = 0; w2 < 8; ++w2) Z += Zl[nn & 1][w2][b32];
            const float rz = __builtin_amdgcn_rcpf(Z);
            const float c00 = e00 * rz, c01 = e01 * rz;
            const float c10 = e10 * rz, c11 = e11 * rz;
#pragma unroll
            for (int k = 0; k < 4; ++k) {
                sacc[0][2 * k + 0] = fmaf(c00, bf_lo(tp0[k]), sacc[0][2 * k + 0]);
                sacc[0][2 * k + 1] = fmaf(c00, bf_hi(tp0[k]), sacc[0][2 * k + 1]);
                sacc[0][2 * k + 8] = fmaf(c01, bf_lo(tp0[k + 4]), sacc[0][2 * k + 8]);
                sacc[0][2 * k + 9] = fmaf(c01, bf_hi(tp0[k + 4]), sacc[0][2 * k + 9]);
                sacc[1][2 * k + 0] = fmaf(c10, bf_lo(tp1[k]), sacc[1][2 * k + 0]);
                sacc[1][2 * k + 1] = fmaf(c10, bf_hi(tp1[k]), sacc[1][2 * k + 1]);
                sacc[1][2 * k + 8] = fmaf(c11, bf_lo(tp1[k + 4]), sacc[1][2 * k + 8]);
                sacc[1][2 * k + 9] = fmaf(c11, bf_hi(tp1[k + 4]), sacc[1][2 * k + 9]);
            }
        }
    }

    // partial[slab][b][od] bf16
#pragma unroll
    for (int m = 0; m < 2; ++m) {
        const int mt = 2 * w + m;
#pragma unroll
        for (int q = 0; q < 4; ++q) {
            const int od = mt * 32 + 8 * q + 4 * hi;
            float v0, v1, v2, v3;
            if (PASS == 0) {
                const f16v& a = (m == 0) ? acc0 : acc1;
                v0 = a[4 * q + 0]; v1 = a[4 * q + 1];
                v2 = a[4 * q + 2]; v3 = a[4 * q + 3];
            } else {
                v0 = sacc[m][4 * q + 0]; v1 = sacc[m][4 * q + 1];
                v2 = sacc[m][4 * q + 2]; v3 = sacc[m][4 * q + 3];
            }
            uint2 u; u.x = pack_bf16(v0, v1); u.y = pack_bf16(v2, v3);
            *reinterpret_cast<uint2*>(
                partial + ((size_t)blk * kB + b) * kSeg + od) = u;
        }
    }
}

// ---------------------------------------------------------------------------
// Finish: sum partials [slab][b][od] over 256 slabs -> s; squash; update
// vsum (+ vsumPack, log2e-scaled, C-row order) / out.
// ---------------------------------------------------------------------------
template<int PASS>
__global__ __launch_bounds__(512, 2)
void caps_finish(const __hip_bfloat16* __restrict__ partial,
                 float* __restrict__ vsum, float* __restrict__ vsumPack,
                 float* __restrict__ out)
{
    const int b  = blockIdx.x >> 2;
    const int q  = blockIdx.x & 3;
    const int t  = threadIdx.x;
    const int tl = t & 127;
    const int cg = t >> 7;
    const int od = q * 128 + tl;

    const __hip_bfloat16* p = partial
        + ((size_t)(cg * 64) * kB + b) * kSeg + od;
    float s = 0.0f;
#pragma unroll 16
    for (int k = 0; k < 64; ++k)
        s += __bfloat162float(p[(size_t)k * (kB * kSeg)]);

    __shared__ float red[4][128];
    __shared__ float sq[128];
    __shared__ float fo[8];
    red[cg][tl] = s;
    __syncthreads();
    if (t < 128) {
        s = (red[0][tl] + red[1][tl]) + (red[2][tl] + red[3][tl]);
        if (PASS == 0) s *= (1.0f / 32.0f);
        sq[tl] = s * s;
    }
    __syncthreads();
    if (t < 8) {
        float n2 = 0.0f;
#pragma unroll
        for (int d = 0; d < 16; ++d) n2 += sq[t * 16 + d];
        fo[t] = sqrtf(n2) / (1.0f + n2);
    }
    __syncthreads();
    if (t < 128) {
        const float v = fo[tl >> 4] * s;
        float nv = v;
        if (PASS == 0) {
            vsum[(size_t)b * kSeg + od] = v;
        } else if (PASS == 1) {
            nv = vsum[(size_t)b * kSeg + od] + v;
            vsum[(size_t)b * kSeg + od] = nv;
        } else {
            out[(size_t)b * kSeg + od] = v;
        }
        if (PASS < 2) {
            const int mt = od >> 5, r5 = od & 31;
            const int hi = (r5 >> 2) & 1, reg = (r5 & 3) | ((r5 >> 3) << 2);
            vsumPack[(((size_t)mt * 2 + hi) * 64 + b) * 16 + reg] =
                nv * 1.44269504f;
        }
    }
}

// ---------------------------------------------------------------------------
extern "C" void kernel_launch(void* const* d_in, const int* in_sizes, int n_in,
                              void* d_out, int out_size, void* d_ws, size_t ws_size,
                              hipStream_t stream)
{
    const float* x = (const float*)d_in[0];   // (64, 2048, 8)
    const float* W = (const float*)d_in[1];   // (2048, 32, 16, 8)
    float* out = (float*)d_out;               // (64, 32, 16)

    char* base = (char*)d_ws;
    __hip_bfloat16* partial = (__hip_bfloat16*)base;                  // 16.78 MB
    base += (size_t)kSlabs * kB * kSeg * sizeof(__hip_bfloat16);
    float* vsum = (float*)base;                                       // 128 KB
    base += (size_t)kB * kSeg * sizeof(float);
    float* vsumPack = (float*)base;                                   // 128 KB
    base += (size_t)16 * 2 * 64 * 16 * sizeof(float);
    unsigned* wPack2 = (unsigned*)base;                               // 16.78 MB
    base += (size_t)kNi * 16 * 64 * 2 * sizeof(unsigned);
    unsigned* xPack = (unsigned*)base;                                // 2 MB

    caps_prep<<<dim3(9216), dim3(256), 0, stream>>>(x, W, wPack2, xPack);

    const dim3 gr(kSlabs * 2), br(512);
    const dim3 gf(kB * 4), bf(512);

    caps_route<0><<<gr, br, 0, stream>>>(wPack2, xPack, vsumPack, partial);
    caps_finish<0><<<gf, bf, 0, stream>>>(partial, vsum, vsumPack, out);
    caps_route<1><<<gr, br, 0, stream>>>(wPack2, xPack, vsumPack, partial);
    caps_finish<1><<<gf, bf, 0, stream>>>(partial, vsum, vsumPack, out);
    caps_route<1><<<gr, br, 0, stream>>>(wPack2, xPack, vsumPack, partial);
    caps_finish<2><<<gf, bf, 0, stream>>>(partial, vsum, vsumPack, out);
}

// Round 13
// 79.410 us; speedup vs baseline: 2.2914x; 2.2914x over previous
//
#include <hip/hip_runtime.h>
#include <hip/hip_bf16.h>
#include <math.h>

namespace {
constexpr int kB  = 64;
constexpr int kNi = 2048;
constexpr int kNo = 32;
constexpr int kDo = 16;
constexpr int kSeg   = kNo * kDo;      // 512 od
constexpr int kSlabs = 256;            // n-slabs
constexpr int kNPer  = kNi / kSlabs;   // 8 n per slab
}

typedef __attribute__((ext_vector_type(4)))  short s4;    // 4 bf16 (2 VGPR)
typedef __attribute__((ext_vector_type(16))) float f16v;  // MFMA C/D

__device__ __forceinline__ f16v mfma_32x32x8_bf16(s4 a, s4 b, f16v c) {
#if __has_builtin(__builtin_amdgcn_mfma_f32_32x32x8bf16_1k)
    return __builtin_amdgcn_mfma_f32_32x32x8bf16_1k(a, b, c, 0, 0, 0);
#else
    asm("v_mfma_f32_32x32x8_bf16 %0, %1, %2, %0" : "+v"(c) : "v"(a), "v"(b));
    return c;
#endif
}

__device__ __forceinline__ unsigned pack_bf16(float lo, float hi) {
    union { __hip_bfloat162 h; unsigned u; } v;
    v.h = __float22bfloat162_rn(make_float2(lo, hi));
    return v.u;
}
__device__ __forceinline__ float bf_lo(unsigned u) { return __uint_as_float(u << 16); }
__device__ __forceinline__ float bf_hi(unsigned u) { return __uint_as_float(u & 0xffff0000u); }

union A2 { int2 i; s4 s; };

// ---------------------------------------------------------------------------
// Prep (verified r10/r11): pack W and x into 32x32x8 MFMA fragment order.
// wPack2 int4 idx ((n*8+w)*64+l): slots {0,1}=mt 2w, {2,3}=mt 2w+1,
//   value = W[n][mt*32+(l&31)][4*(l>>5)+j].
// xPack int2 idx ((n*2+nt)*64+l) = x[nt*32+(l&31)][n][4*(l>>5)+j].
// ---------------------------------------------------------------------------
__global__ __launch_bounds__(256, 4)
void caps_prep(const float* __restrict__ xg, const float* __restrict__ Wg,
               unsigned* __restrict__ wPack2, unsigned* __restrict__ xPack)
{
    const int t = blockIdx.x * 256 + threadIdx.x;
    const int nW = kNi * 16 * 64;
    if (t < nW) {
        const int n = t >> 10, rem = t & 1023, mt = rem >> 6, l = rem & 63;
        const float4 w = *reinterpret_cast<const float4*>(
            Wg + ((size_t)n * kSeg + mt * 32 + (l & 31)) * 8 + 4 * (l >> 5));
        const size_t base = (((size_t)n * 8 + (mt >> 1)) * 64 + l) * 4 + (mt & 1) * 2;
        uint2 u; u.x = pack_bf16(w.x, w.y); u.y = pack_bf16(w.z, w.w);
        *reinterpret_cast<uint2*>(wPack2 + base) = u;
    } else {
        const int t2 = t - nW;
        const int n = t2 >> 7, rem = t2 & 127, nt = rem >> 6, l = rem & 63;
        const float4 v = *reinterpret_cast<const float4*>(
            xg + ((size_t)(nt * 32 + (l & 31)) * kNi + n) * 8 + 4 * (l >> 5));
        uint2 u; u.x = pack_bf16(v.x, v.y); u.y = pack_bf16(v.z, v.w);
        *reinterpret_cast<uint2*>(xPack + (size_t)t2 * 2) = u;
    }
}

// C/D layout (m74/m101-verified): col = l&31 (= b),
// row = (reg&3)+8*(reg>>2)+4*(l>>5); regs 0-7 -> o=2mt, regs 8-15 -> o=2mt+1.

// ---------------------------------------------------------------------------
// Pass 0: s0 = sum_n x_hat (uniform c; 1/32 applied in finish). r11-verified.
// ---------------------------------------------------------------------------
__global__ __launch_bounds__(512, 2)
void caps_acc0(const unsigned* __restrict__ wPack2, const unsigned* __restrict__ xPack,
               __hip_bfloat16* __restrict__ partial)
{
    const int tid = threadIdx.x;
    const int blk = blockIdx.x & (kSlabs - 1);
    const int nt  = blockIdx.x >> 8;
    const int w   = __builtin_amdgcn_readfirstlane(tid >> 6);
    const int l   = tid & 63;
    const int b   = nt * 32 + (l & 31);
    const int hi  = l >> 5;

    f16v acc0, acc1;
#pragma unroll
    for (int r = 0; r < 16; ++r) { acc0[r] = 0.0f; acc1[r] = 0.0f; }

    const int4* wp4 = reinterpret_cast<const int4*>(wPack2);
    const int2* xp2 = reinterpret_cast<const int2*>(xPack);
    const size_t abase = ((size_t)blk * 64 + w) * 64 + l;
    const size_t xbase = ((size_t)blk * 16 + nt) * 64 + l;

#pragma unroll 2
    for (int nn = 0; nn < kNPer; ++nn) {
        const int4 aw = wp4[abase + (size_t)nn * 512];
        const int2 bx = xp2[xbase + (size_t)nn * 128];
        A2 ua0; ua0.i = make_int2(aw.x, aw.y);
        A2 ua1; ua1.i = make_int2(aw.z, aw.w);
        A2 ub;  ub.i  = bx;
        acc0 = mfma_32x32x8_bf16(ua0.s, ub.s, acc0);
        acc1 = mfma_32x32x8_bf16(ua1.s, ub.s, acc1);
    }

#pragma unroll
    for (int m = 0; m < 2; ++m) {
        const int mt = 2 * w + m;
        const f16v& a = (m == 0) ? acc0 : acc1;
#pragma unroll
        for (int q = 0; q < 4; ++q) {
            const int od = mt * 32 + 8 * q + 4 * hi;
            uint2 u;
            u.x = pack_bf16(a[4 * q + 0], a[4 * q + 1]);
            u.y = pack_bf16(a[4 * q + 2], a[4 * q + 3]);
            *reinterpret_cast<uint2*>(
                partial + ((size_t)blk * kB + b) * kSeg + od) = u;
        }
    }
}

// ---------------------------------------------------------------------------
// Fused routing iteration: phase L (r11 caps_logits) then phase A (r11
// caps_accum<1>), c parked in LDS (cl[nn][mt][b32]; each wave reads only its
// own writes). Phases are SEQUENTIAL -> VGPR = max(~95, ~90), not the sum
// (r12's mistake). sched_barrier(0) stops phase-A loads hoisting into L.
// Phase-A pack re-reads are L2-hits (block just streamed them).
// ---------------------------------------------------------------------------
__global__ __launch_bounds__(512, 2)
void caps_routef(const unsigned* __restrict__ wPack2, const unsigned* __restrict__ xPack,
                 const float* __restrict__ vsumPack, __hip_bfloat16* __restrict__ partial)
{
    __shared__ float Zl[2][8][4][32];       // 8 KB
    __shared__ unsigned cl[kNPer][16][32];  // 16 KB

    const int tid = threadIdx.x;
    const int blk = blockIdx.x & (kSlabs - 1);
    const int nt  = blockIdx.x >> 8;
    const int w   = __builtin_amdgcn_readfirstlane(tid >> 6);
    const int l   = tid & 63;
    const int b32 = l & 31;
    const int b   = nt * 32 + b32;
    const int hi  = l >> 5;

    const int4* wp4 = reinterpret_cast<const int4*>(wPack2);
    const int2* xp2 = reinterpret_cast<const int2*>(xPack);
    const size_t abase = ((size_t)blk * 64 + w) * 64 + l;          // +nn*512
    const size_t xbase = ((size_t)blk * 16 + nt) * 64 + l;         // +nn*128

    // ---- phase L: couplings into LDS ----
    {
        // vsum fragments (f32, C-row order, pre-scaled by log2 e)
        float vsp[2][16];
#pragma unroll
        for (int m = 0; m < 2; ++m) {
            const int mt = 2 * w + m;
            const float4* vp = reinterpret_cast<const float4*>(
                vsumPack + (((size_t)mt * 2 + hi) * 64 + b) * 16);
#pragma unroll
            for (int k = 0; k < 4; ++k) {
                const float4 v = vp[k];
                vsp[m][4 * k + 0] = v.x; vsp[m][4 * k + 1] = v.y;
                vsp[m][4 * k + 2] = v.z; vsp[m][4 * k + 3] = v.w;
            }
        }

        for (int h = 0; h < 2; ++h) {
            float e[4][4];
#pragma unroll
            for (int k = 0; k < 4; ++k) {
                const int nn = h * 4 + k;
                const int4 aw = wp4[abase + (size_t)nn * 512];
                const int2 bx = xp2[xbase + (size_t)nn * 128];
                A2 ua0; ua0.i = make_int2(aw.x, aw.y);
                A2 ua1; ua1.i = make_int2(aw.z, aw.w);
                A2 ub;  ub.i  = bx;
                f16v t0, t1;
#pragma unroll
                for (int r = 0; r < 16; ++r) { t0[r] = 0.0f; t1[r] = 0.0f; }
                t0 = mfma_32x32x8_bf16(ua0.s, ub.s, t0);
                t1 = mfma_32x32x8_bf16(ua1.s, ub.s, t1);
                {
                    float a0_ = fmaf(vsp[0][1], t0[1], vsp[0][0] * t0[0]);
                    float a1_ = fmaf(vsp[0][3], t0[3], vsp[0][2] * t0[2]);
                    float a2_ = fmaf(vsp[0][5], t0[5], vsp[0][4] * t0[4]);
                    float a3_ = fmaf(vsp[0][7], t0[7], vsp[0][6] * t0[6]);
                    float p0 = (a0_ + a1_) + (a2_ + a3_);
                    float b0_ = fmaf(vsp[0][9],  t0[9],  vsp[0][8]  * t0[8]);
                    float b1_ = fmaf(vsp[0][11], t0[11], vsp[0][10] * t0[10]);
                    float b2_ = fmaf(vsp[0][13], t0[13], vsp[0][12] * t0[12]);
                    float b3_ = fmaf(vsp[0][15], t0[15], vsp[0][14] * t0[14]);
                    float p1 = (b0_ + b1_) + (b2_ + b3_);
                    p0 += __shfl_xor(p0, 32);
                    p1 += __shfl_xor(p1, 32);
                    e[k][0] = exp2f(p0); e[k][1] = exp2f(p1);
                }
                {
                    float a0_ = fmaf(vsp[1][1], t1[1], vsp[1][0] * t1[0]);
                    float a1_ = fmaf(vsp[1][3], t1[3], vsp[1][2] * t1[2]);
                    float a2_ = fmaf(vsp[1][5], t1[5], vsp[1][4] * t1[4]);
                    float a3_ = fmaf(vsp[1][7], t1[7], vsp[1][6] * t1[6]);
                    float p0 = (a0_ + a1_) + (a2_ + a3_);
                    float b0_ = fmaf(vsp[1][9],  t1[9],  vsp[1][8]  * t1[8]);
                    float b1_ = fmaf(vsp[1][11], t1[11], vsp[1][10] * t1[10]);
                    float b2_ = fmaf(vsp[1][13], t1[13], vsp[1][12] * t1[12]);
                    float b3_ = fmaf(vsp[1][15], t1[15], vsp[1][14] * t1[14]);
                    float p1 = (b0_ + b1_) + (b2_ + b3_);
                    p0 += __shfl_xor(p0, 32);
                    p1 += __shfl_xor(p1, 32);
                    e[k][2] = exp2f(p0); e[k][3] = exp2f(p1);
                }
                if (l < 32)
                    Zl[h][w][k][l] = (e[k][0] + e[k][1]) + (e[k][2] + e[k][3]);
            }
            __syncthreads();
#pragma unroll
            for (int k = 0; k < 4; ++k) {
                float Z = 0.0f;
#pragma unroll
                for (int w2 = 0; w2 < 8; ++w2) Z += Zl[h][w2][k][b32];
                const float rz = __builtin_amdgcn_rcpf(Z);
                if (l < 32) {
                    cl[h * 4 + k][2 * w + 0][l] = pack_bf16(e[k][0] * rz, e[k][1] * rz);
                    cl[h * 4 + k][2 * w + 1][l] = pack_bf16(e[k][2] * rz, e[k][3] * rz);
                }
            }
        }
    }
    __syncthreads();
    __builtin_amdgcn_sched_barrier(0);   // keep phase-A loads out of phase L

    // ---- phase A: s accumulation (sacc live; vsp dead) ----
    float sacc[2][16];
#pragma unroll
    for (int r = 0; r < 16; ++r) { sacc[0][r] = 0.0f; sacc[1][r] = 0.0f; }

#pragma unroll 2
    for (int nn = 0; nn < kNPer; ++nn) {
        const int4 aw = wp4[abase + (size_t)nn * 512];
        const int2 bx = xp2[xbase + (size_t)nn * 128];
        A2 ua0; ua0.i = make_int2(aw.x, aw.y);
        A2 ua1; ua1.i = make_int2(aw.z, aw.w);
        A2 ub;  ub.i  = bx;
        const unsigned cp0 = cl[nn][2 * w + 0][b32];
        const unsigned cp1 = cl[nn][2 * w + 1][b32];
        f16v t0, t1;
#pragma unroll
        for (int r = 0; r < 16; ++r) { t0[r] = 0.0f; t1[r] = 0.0f; }
        t0 = mfma_32x32x8_bf16(ua0.s, ub.s, t0);
        t1 = mfma_32x32x8_bf16(ua1.s, ub.s, t1);
        const float c00 = bf_lo(cp0), c01 = bf_hi(cp0);
        const float c10 = bf_lo(cp1), c11 = bf_hi(cp1);
#pragma unroll
        for (int r = 0; r < 8; ++r) {
            sacc[0][r]     = fmaf(c00, t0[r],     sacc[0][r]);
            sacc[0][8 + r] = fmaf(c01, t0[8 + r], sacc[0][8 + r]);
            sacc[1][r]     = fmaf(c10, t1[r],     sacc[1][r]);
            sacc[1][8 + r] = fmaf(c11, t1[8 + r], sacc[1][8 + r]);
        }
    }

    // partial[slab][b][od] bf16
#pragma unroll
    for (int m = 0; m < 2; ++m) {
        const int mt = 2 * w + m;
#pragma unroll
        for (int q = 0; q < 4; ++q) {
            const int od = mt * 32 + 8 * q + 4 * hi;
            uint2 u;
            u.x = pack_bf16(sacc[m][4 * q + 0], sacc[m][4 * q + 1]);
            u.y = pack_bf16(sacc[m][4 * q + 2], sacc[m][4 * q + 3]);
            *reinterpret_cast<uint2*>(
                partial + ((size_t)blk * kB + b) * kSeg + od) = u;
        }
    }
}

// ---------------------------------------------------------------------------
// Finish (r11-verified): sum partials over 256 slabs -> s; squash; update
// vsum (+ vsumPack, log2e-scaled, C-row order) / out.
// ---------------------------------------------------------------------------
template<int PASS>
__global__ __launch_bounds__(512, 2)
void caps_finish(const __hip_bfloat16* __restrict__ partial,
                 float* __restrict__ vsum, float* __restrict__ vsumPack,
                 float* __restrict__ out)
{
    const int b  = blockIdx.x >> 2;
    const int q  = blockIdx.x & 3;
    const int t  = threadIdx.x;
    const int tl = t & 127;
    const int cg = t >> 7;
    const int od = q * 128 + tl;

    const __hip_bfloat16* p = partial
        + ((size_t)(cg * 64) * kB + b) * kSeg + od;
    float s = 0.0f;
#pragma unroll 16
    for (int k = 0; k < 64; ++k)
        s += __bfloat162float(p[(size_t)k * (kB * kSeg)]);

    __shared__ float red[4][128];
    __shared__ float sq[128];
    __shared__ float fo[8];
    red[cg][tl] = s;
    __syncthreads();
    if (t < 128) {
        s = (red[0][tl] + red[1][tl]) + (red[2][tl] + red[3][tl]);
        if (PASS == 0) s *= (1.0f / 32.0f);
        sq[tl] = s * s;
    }
    __syncthreads();
    if (t < 8) {
        float n2 = 0.0f;
#pragma unroll
        for (int d = 0; d < 16; ++d) n2 += sq[t * 16 + d];
        fo[t] = sqrtf(n2) / (1.0f + n2);
    }
    __syncthreads();
    if (t < 128) {
        const float v = fo[tl >> 4] * s;
        float nv = v;
        if (PASS == 0) {
            vsum[(size_t)b * kSeg + od] = v;
        } else if (PASS == 1) {
            nv = vsum[(size_t)b * kSeg + od] + v;
            vsum[(size_t)b * kSeg + od] = nv;
        } else {
            out[(size_t)b * kSeg + od] = v;
        }
        if (PASS < 2) {
            const int mt = od >> 5, r5 = od & 31;
            const int hi = (r5 >> 2) & 1, reg = (r5 & 3) | ((r5 >> 3) << 2);
            vsumPack[(((size_t)mt * 2 + hi) * 64 + b) * 16 + reg] =
                nv * 1.44269504f;
        }
    }
}

// ---------------------------------------------------------------------------
extern "C" void kernel_launch(void* const* d_in, const int* in_sizes, int n_in,
                              void* d_out, int out_size, void* d_ws, size_t ws_size,
                              hipStream_t stream)
{
    const float* x = (const float*)d_in[0];   // (64, 2048, 8)
    const float* W = (const float*)d_in[1];   // (2048, 32, 16, 8)
    float* out = (float*)d_out;               // (64, 32, 16)

    char* base = (char*)d_ws;
    __hip_bfloat16* partial = (__hip_bfloat16*)base;                  // 16.78 MB
    base += (size_t)kSlabs * kB * kSeg * sizeof(__hip_bfloat16);
    float* vsum = (float*)base;                                       // 128 KB
    base += (size_t)kB * kSeg * sizeof(float);
    float* vsumPack = (float*)base;                                   // 128 KB
    base += (size_t)16 * 2 * 64 * 16 * sizeof(float);
    unsigned* wPack2 = (unsigned*)base;                               // 16.78 MB
    base += (size_t)kNi * 16 * 64 * 2 * sizeof(unsigned);
    unsigned* xPack = (unsigned*)base;                                // 2 MB

    caps_prep<<<dim3(9216), dim3(256), 0, stream>>>(x, W, wPack2, xPack);

    const dim3 gr(kSlabs * 2), br(512);
    const dim3 gf(kB * 4), bf(512);

    caps_acc0<<<gr, br, 0, stream>>>(wPack2, xPack, partial);
    caps_finish<0><<<gf, bf, 0, stream>>>(partial, vsum, vsumPack, out);
    caps_routef<<<gr, br, 0, stream>>>(wPack2, xPack, vsumPack, partial);
    caps_finish<1><<<gf, bf, 0, stream>>>(partial, vsum, vsumPack, out);
    caps_routef<<<gr, br, 0, stream>>>(wPack2, xPack, vsumPack, partial);
    caps_finish<2><<<gf, bf, 0, stream>>>(partial, vsum, vsumPack, out);
}

// Round 14
// 71.874 us; speedup vs baseline: 2.5316x; 1.1048x over previous
//
#include <hip/hip_runtime.h>
#include <hip/hip_bf16.h>
#include <math.h>

namespace {
constexpr int kB  = 64;
constexpr int kNi = 2048;
constexpr int kNo = 32;
constexpr int kDo = 16;
constexpr int kSeg   = kNo * kDo;      // 512 od (od = o*16 + d)
constexpr int kSlabs = 256;            // n-slabs
constexpr int kNPer  = kNi / kSlabs;   // 8 n per slab
}

typedef __attribute__((ext_vector_type(4)))  short s4;    // 4 bf16 (2 VGPR)
typedef __attribute__((ext_vector_type(16))) float f16v;  // MFMA C/D

__device__ __forceinline__ f16v mfma_32x32x8_bf16(s4 a, s4 b, f16v c) {
#if __has_builtin(__builtin_amdgcn_mfma_f32_32x32x8bf16_1k)
    return __builtin_amdgcn_mfma_f32_32x32x8bf16_1k(a, b, c, 0, 0, 0);
#else
    asm("v_mfma_f32_32x32x8_bf16 %0, %1, %2, %0" : "+v"(c) : "v"(a), "v"(b));
    return c;
#endif
}

__device__ __forceinline__ unsigned pack_bf16(float lo, float hi) {
    union { __hip_bfloat162 h; unsigned u; } v;
    v.h = __float22bfloat162_rn(make_float2(lo, hi));
    return v.u;
}
__device__ __forceinline__ float bf_lo(unsigned u) { return __uint_as_float(u << 16); }
__device__ __forceinline__ float bf_hi(unsigned u) { return __uint_as_float(u & 0xffff0000u); }

union A2 { int2 i; s4 s; };

// C/D layout (m74/m101-verified): col = l&31 (= b),
// row = (reg&3)+8*(reg>>2)+4*(l>>5); regs 0-7 -> o=2mt, regs 8-15 -> o=2mt+1.

// ---------------------------------------------------------------------------
// Fused prep + pass-0. Grid 256 (one block per n-slab), 8 waves.
// Wave w owns mt {2w, 2w+1} for BOTH b-halves. Per nn: load W f32 (coalesced
// 2KB/tile-row pattern), pack -> registers -> wPack2 (int4) AND feed MFMA
// directly; same for x (gather, same pattern prep used) -> xPack.
// Pass-0 accumulators acc[nt][m] = 4 f16v (64 VGPR); live ~110 <= 128 cap.
// Uniform coupling: 1/32 applied in finish<0>.
// ---------------------------------------------------------------------------
__global__ __launch_bounds__(512, 2)
void caps_prepacc(const float* __restrict__ xg, const float* __restrict__ Wg,
                  unsigned* __restrict__ wPack2, unsigned* __restrict__ xPack,
                  __hip_bfloat16* __restrict__ partial)
{
    const int tid = threadIdx.x;
    const int blk = blockIdx.x;                    // slab 0..255
    const int w   = __builtin_amdgcn_readfirstlane(tid >> 6);
    const int l   = tid & 63;
    const int o32 = l & 31;
    const int hi  = l >> 5;

    const float4* Wg4 = reinterpret_cast<const float4*>(Wg);
    const float4* xg4 = reinterpret_cast<const float4*>(xg);

    f16v acc00, acc01, acc10, acc11;   // [nt][m], static names (rule #20)
#pragma unroll
    for (int r = 0; r < 16; ++r) {
        acc00[r] = 0.0f; acc01[r] = 0.0f; acc10[r] = 0.0f; acc11[r] = 0.0f;
    }

#pragma unroll 2
    for (int nn = 0; nn < kNPer; ++nn) {
        const int n = blk * kNPer + nn;
        // W fragments for my two m-tiles (f32 -> bf16 pack)
        const float4 w0 = Wg4[((size_t)n * 512 + (2 * w + 0) * 32 + o32) * 2 + hi];
        const float4 w1 = Wg4[((size_t)n * 512 + (2 * w + 1) * 32 + o32) * 2 + hi];
        int4 wp;
        wp.x = (int)pack_bf16(w0.x, w0.y);
        wp.y = (int)pack_bf16(w0.z, w0.w);
        wp.z = (int)pack_bf16(w1.x, w1.y);
        wp.w = (int)pack_bf16(w1.z, w1.w);
        reinterpret_cast<int4*>(wPack2)[((size_t)n * 8 + w) * 64 + l] = wp;

        // x fragments for both b-halves
        const float4 x0 = xg4[((size_t)(0 * 32 + o32) * kNi + n) * 2 + hi];
        const float4 x1 = xg4[((size_t)(32 + o32) * kNi + n) * 2 + hi];
        uint2 q0, q1;
        q0.x = pack_bf16(x0.x, x0.y); q0.y = pack_bf16(x0.z, x0.w);
        q1.x = pack_bf16(x1.x, x1.y); q1.y = pack_bf16(x1.z, x1.w);
        *reinterpret_cast<uint2*>(xPack + ((size_t)(n * 2 + 0) * 64 + l) * 2) = q0;
        *reinterpret_cast<uint2*>(xPack + ((size_t)(n * 2 + 1) * 64 + l) * 2) = q1;

        A2 a0; a0.i = make_int2(wp.x, wp.y);
        A2 a1; a1.i = make_int2(wp.z, wp.w);
        A2 b0; b0.i = make_int2((int)q0.x, (int)q0.y);
        A2 b1; b1.i = make_int2((int)q1.x, (int)q1.y);
        acc00 = mfma_32x32x8_bf16(a0.s, b0.s, acc00);
        acc01 = mfma_32x32x8_bf16(a1.s, b0.s, acc01);
        acc10 = mfma_32x32x8_bf16(a0.s, b1.s, acc10);
        acc11 = mfma_32x32x8_bf16(a1.s, b1.s, acc11);
    }

    // partial[slab][b][od] bf16
#pragma unroll
    for (int nt = 0; nt < 2; ++nt) {
        const int b = nt * 32 + o32;
#pragma unroll
        for (int m = 0; m < 2; ++m) {
            const int mt = 2 * w + m;
            const f16v& a = (nt == 0) ? (m == 0 ? acc00 : acc01)
                                      : (m == 0 ? acc10 : acc11);
#pragma unroll
            for (int q = 0; q < 4; ++q) {
                const int od = mt * 32 + 8 * q + 4 * hi;
                uint2 u;
                u.x = pack_bf16(a[4 * q + 0], a[4 * q + 1]);
                u.y = pack_bf16(a[4 * q + 2], a[4 * q + 3]);
                *reinterpret_cast<uint2*>(
                    partial + ((size_t)blk * kB + b) * kSeg + od) = u;
            }
        }
    }
}

// ---------------------------------------------------------------------------
// Fused routing iteration (r13-verified, unchanged): phase L (logits -> c in
// LDS) then phase A (accumulate). Sequential register profiles -> no spill.
// ---------------------------------------------------------------------------
__global__ __launch_bounds__(512, 2)
void caps_routef(const unsigned* __restrict__ wPack2, const unsigned* __restrict__ xPack,
                 const float* __restrict__ vsumPack, __hip_bfloat16* __restrict__ partial)
{
    __shared__ float Zl[2][8][4][32];       // 8 KB
    __shared__ unsigned cl[kNPer][16][32];  // 16 KB

    const int tid = threadIdx.x;
    const int blk = blockIdx.x & (kSlabs - 1);
    const int nt  = blockIdx.x >> 8;
    const int w   = __builtin_amdgcn_readfirstlane(tid >> 6);
    const int l   = tid & 63;
    const int b32 = l & 31;
    const int b   = nt * 32 + b32;
    const int hi  = l >> 5;

    const int4* wp4 = reinterpret_cast<const int4*>(wPack2);
    const int2* xp2 = reinterpret_cast<const int2*>(xPack);
    const size_t abase = ((size_t)blk * 64 + w) * 64 + l;          // +nn*512
    const size_t xbase = ((size_t)blk * 16 + nt) * 64 + l;         // +nn*128

    // ---- phase L: couplings into LDS ----
    {
        float vsp[2][16];
#pragma unroll
        for (int m = 0; m < 2; ++m) {
            const int mt = 2 * w + m;
            const float4* vp = reinterpret_cast<const float4*>(
                vsumPack + (((size_t)mt * 2 + hi) * 64 + b) * 16);
#pragma unroll
            for (int k = 0; k < 4; ++k) {
                const float4 v = vp[k];
                vsp[m][4 * k + 0] = v.x; vsp[m][4 * k + 1] = v.y;
                vsp[m][4 * k + 2] = v.z; vsp[m][4 * k + 3] = v.w;
            }
        }

        for (int h = 0; h < 2; ++h) {
            float e[4][4];
#pragma unroll
            for (int k = 0; k < 4; ++k) {
                const int nn = h * 4 + k;
                const int4 aw = wp4[abase + (size_t)nn * 512];
                const int2 bx = xp2[xbase + (size_t)nn * 128];
                A2 ua0; ua0.i = make_int2(aw.x, aw.y);
                A2 ua1; ua1.i = make_int2(aw.z, aw.w);
                A2 ub;  ub.i  = bx;
                f16v t0, t1;
#pragma unroll
                for (int r = 0; r < 16; ++r) { t0[r] = 0.0f; t1[r] = 0.0f; }
                t0 = mfma_32x32x8_bf16(ua0.s, ub.s, t0);
                t1 = mfma_32x32x8_bf16(ua1.s, ub.s, t1);
                {
                    float a0_ = fmaf(vsp[0][1], t0[1], vsp[0][0] * t0[0]);
                    float a1_ = fmaf(vsp[0][3], t0[3], vsp[0][2] * t0[2]);
                    float a2_ = fmaf(vsp[0][5], t0[5], vsp[0][4] * t0[4]);
                    float a3_ = fmaf(vsp[0][7], t0[7], vsp[0][6] * t0[6]);
                    float p0 = (a0_ + a1_) + (a2_ + a3_);
                    float b0_ = fmaf(vsp[0][9],  t0[9],  vsp[0][8]  * t0[8]);
                    float b1_ = fmaf(vsp[0][11], t0[11], vsp[0][10] * t0[10]);
                    float b2_ = fmaf(vsp[0][13], t0[13], vsp[0][12] * t0[12]);
                    float b3_ = fmaf(vsp[0][15], t0[15], vsp[0][14] * t0[14]);
                    float p1 = (b0_ + b1_) + (b2_ + b3_);
                    p0 += __shfl_xor(p0, 32);
                    p1 += __shfl_xor(p1, 32);
                    e[k][0] = exp2f(p0); e[k][1] = exp2f(p1);
                }
                {
                    float a0_ = fmaf(vsp[1][1], t1[1], vsp[1][0] * t1[0]);
                    float a1_ = fmaf(vsp[1][3], t1[3], vsp[1][2] * t1[2]);
                    float a2_ = fmaf(vsp[1][5], t1[5], vsp[1][4] * t1[4]);
                    float a3_ = fmaf(vsp[1][7], t1[7], vsp[1][6] * t1[6]);
                    float p0 = (a0_ + a1_) + (a2_ + a3_);
                    float b0_ = fmaf(vsp[1][9],  t1[9],  vsp[1][8]  * t1[8]);
                    float b1_ = fmaf(vsp[1][11], t1[11], vsp[1][10] * t1[10]);
                    float b2_ = fmaf(vsp[1][13], t1[13], vsp[1][12] * t1[12]);
                    float b3_ = fmaf(vsp[1][15], t1[15], vsp[1][14] * t1[14]);
                    float p1 = (b0_ + b1_) + (b2_ + b3_);
                    p0 += __shfl_xor(p0, 32);
                    p1 += __shfl_xor(p1, 32);
                    e[k][2] = exp2f(p0); e[k][3] = exp2f(p1);
                }
                if (l < 32)
                    Zl[h][w][k][l] = (e[k][0] + e[k][1]) + (e[k][2] + e[k][3]);
            }
            __syncthreads();
#pragma unroll
            for (int k = 0; k < 4; ++k) {
                float Z = 0.0f;
#pragma unroll
                for (int w2 = 0; w2 < 8; ++w2) Z += Zl[h][w2][k][b32];
                const float rz = __builtin_amdgcn_rcpf(Z);
                if (l < 32) {
                    cl[h * 4 + k][2 * w + 0][l] = pack_bf16(e[k][0] * rz, e[k][1] * rz);
                    cl[h * 4 + k][2 * w + 1][l] = pack_bf16(e[k][2] * rz, e[k][3] * rz);
                }
            }
        }
    }
    __syncthreads();
    __builtin_amdgcn_sched_barrier(0);   // keep phase-A loads out of phase L

    // ---- phase A: s accumulation (sacc live; vsp dead) ----
    float sacc[2][16];
#pragma unroll
    for (int r = 0; r < 16; ++r) { sacc[0][r] = 0.0f; sacc[1][r] = 0.0f; }

#pragma unroll 2
    for (int nn = 0; nn < kNPer; ++nn) {
        const int4 aw = wp4[abase + (size_t)nn * 512];
        const int2 bx = xp2[xbase + (size_t)nn * 128];
        A2 ua0; ua0.i = make_int2(aw.x, aw.y);
        A2 ua1; ua1.i = make_int2(aw.z, aw.w);
        A2 ub;  ub.i  = bx;
        const unsigned cp0 = cl[nn][2 * w + 0][b32];
        const unsigned cp1 = cl[nn][2 * w + 1][b32];
        f16v t0, t1;
#pragma unroll
        for (int r = 0; r < 16; ++r) { t0[r] = 0.0f; t1[r] = 0.0f; }
        t0 = mfma_32x32x8_bf16(ua0.s, ub.s, t0);
        t1 = mfma_32x32x8_bf16(ua1.s, ub.s, t1);
        const float c00 = bf_lo(cp0), c01 = bf_hi(cp0);
        const float c10 = bf_lo(cp1), c11 = bf_hi(cp1);
#pragma unroll
        for (int r = 0; r < 8; ++r) {
            sacc[0][r]     = fmaf(c00, t0[r],     sacc[0][r]);
            sacc[0][8 + r] = fmaf(c01, t0[8 + r], sacc[0][8 + r]);
            sacc[1][r]     = fmaf(c10, t1[r],     sacc[1][r]);
            sacc[1][8 + r] = fmaf(c11, t1[8 + r], sacc[1][8 + r]);
        }
    }

    // partial[slab][b][od] bf16
#pragma unroll
    for (int m = 0; m < 2; ++m) {
        const int mt = 2 * w + m;
#pragma unroll
        for (int q = 0; q < 4; ++q) {
            const int od = mt * 32 + 8 * q + 4 * hi;
            uint2 u;
            u.x = pack_bf16(sacc[m][4 * q + 0], sacc[m][4 * q + 1]);
            u.y = pack_bf16(sacc[m][4 * q + 2], sacc[m][4 * q + 3]);
            *reinterpret_cast<uint2*>(
                partial + ((size_t)blk * kB + b) * kSeg + od) = u;
        }
    }
}

// ---------------------------------------------------------------------------
// Finish, vectorized: thread owns an od-quad x 16-slab group -> uint2 loads
// (4 bf16 each; 512 B per wave transaction, 4x fewer load instrs than 2B
// scalar). 16-group LDS tree -> squash -> vsum/vsumPack/out.
// ---------------------------------------------------------------------------
template<int PASS>
__global__ __launch_bounds__(512, 2)
void caps_finish(const __hip_bfloat16* __restrict__ partial,
                 float* __restrict__ vsum, float* __restrict__ vsumPack,
                 float* __restrict__ out)
{
    const int b  = blockIdx.x >> 2;
    const int q  = blockIdx.x & 3;
    const int t  = threadIdx.x;
    const int qd = t & 31;            // od-quad within my 128-od quarter
    const int sg = t >> 5;            // slab group 0..15 (16 slabs each)
    const int od0 = q * 128 + qd * 4;

    const __hip_bfloat16* p = partial
        + ((size_t)(sg * 16) * kB + b) * kSeg + od0;
    float s0 = 0, s1 = 0, s2 = 0, s3 = 0;
#pragma unroll
    for (int k = 0; k < 16; ++k) {
        const uint2 u = *reinterpret_cast<const uint2*>(p + (size_t)k * (kB * kSeg));
        s0 += bf_lo(u.x); s1 += bf_hi(u.x);
        s2 += bf_lo(u.y); s3 += bf_hi(u.y);
    }

    __shared__ float red[16][128];
    __shared__ float sq[128];
    __shared__ float fo[8];
    *reinterpret_cast<float4*>(&red[sg][qd * 4]) = make_float4(s0, s1, s2, s3);
    __syncthreads();
    if (t < 128) {
        float s = 0.0f;
#pragma unroll
        for (int g = 0; g < 16; ++g) s += red[g][t];
        if (PASS == 0) s *= (1.0f / 32.0f);   // uniform coupling 1/No
        sq[t] = s * s;
        red[0][t] = s;    // own-column reuse (each thread reads/writes col t only)
    }
    __syncthreads();
    if (t < 8) {
        float n2 = 0.0f;
#pragma unroll
        for (int d = 0; d < 16; ++d) n2 += sq[t * 16 + d];
        fo[t] = sqrtf(n2) / (1.0f + n2);   // ||s|| / (1 + ||s||^2)
    }
    __syncthreads();
    if (t < 128) {
        const float s = red[0][t];
        const int od = q * 128 + t;
        const float v = fo[t >> 4] * s;
        float nv = v;
        if (PASS == 0) {
            vsum[(size_t)b * kSeg + od] = v;
        } else if (PASS == 1) {
            nv = vsum[(size_t)b * kSeg + od] + v;
            vsum[(size_t)b * kSeg + od] = nv;
        } else {
            out[(size_t)b * kSeg + od] = v;
        }
        if (PASS < 2) {
            // invert C-row map: row = (reg&3) + 8*(reg>>2) + 4*hi
            const int mt = od >> 5, r5 = od & 31;
            const int hi = (r5 >> 2) & 1, reg = (r5 & 3) | ((r5 >> 3) << 2);
            vsumPack[(((size_t)mt * 2 + hi) * 64 + b) * 16 + reg] =
                nv * 1.44269504f;
        }
    }
}

// ---------------------------------------------------------------------------
extern "C" void kernel_launch(void* const* d_in, const int* in_sizes, int n_in,
                              void* d_out, int out_size, void* d_ws, size_t ws_size,
                              hipStream_t stream)
{
    const float* x = (const float*)d_in[0];   // (64, 2048, 8)
    const float* W = (const float*)d_in[1];   // (2048, 32, 16, 8)
    float* out = (float*)d_out;               // (64, 32, 16)

    char* base = (char*)d_ws;
    __hip_bfloat16* partial = (__hip_bfloat16*)base;                  // 16.78 MB
    base += (size_t)kSlabs * kB * kSeg * sizeof(__hip_bfloat16);
    float* vsum = (float*)base;                                       // 128 KB
    base += (size_t)kB * kSeg * sizeof(float);
    float* vsumPack = (float*)base;                                   // 128 KB
    base += (size_t)16 * 2 * 64 * 16 * sizeof(float);
    unsigned* wPack2 = (unsigned*)base;                               // 16.78 MB
    base += (size_t)kNi * 16 * 64 * 2 * sizeof(unsigned);
    unsigned* xPack = (unsigned*)base;                                // 2 MB

    const dim3 gp(kSlabs), bp(512);
    const dim3 gr(kSlabs * 2), br(512);
    const dim3 gf(kB * 4), bf(512);

    caps_prepacc<<<gp, bp, 0, stream>>>(x, W, wPack2, xPack, partial);
    caps_finish<0><<<gf, bf, 0, stream>>>(partial, vsum, vsumPack, out);
    caps_routef<<<gr, br, 0, stream>>>(wPack2, xPack, vsumPack, partial);
    caps_finish<1><<<gf, bf, 0, stream>>>(partial, vsum, vsumPack, out);
    caps_routef<<<gr, br, 0, stream>>>(wPack2, xPack, vsumPack, partial);
    caps_finish<2><<<gf, bf, 0, stream>>>(partial, vsum, vsumPack, out);
}